// Round 1
// baseline (5430.649 us; speedup 1.0000x reference)
//
#include <hip/hip_runtime.h>

#define MEDNUM 50000
#define FEATDIM 128
#define NNZ 3200000
#define NROWS (2 * MEDNUM)

// ---------------------------------------------------------------------------
// Kernel 1: zero the aggregation workspace (float4 stores)
// ---------------------------------------------------------------------------
__global__ void zero4_kernel(float4* __restrict__ p, int n4) {
    int i = blockIdx.x * blockDim.x + threadIdx.x;
    if (i < n4) p[i] = make_float4(0.f, 0.f, 0.f, 0.f);
}

// ---------------------------------------------------------------------------
// Kernel 2: scatter-add. 32 threads per edge; each thread handles 4 features.
// Lane group 0..31 of an edge loads a contiguous float4 of the embedding row
// (512 B coalesced) and atomically adds val*embed into agg[row].
// ---------------------------------------------------------------------------
__global__ void scatter_kernel(const float* __restrict__ vals,
                               const float* __restrict__ mEmbed,
                               const int* __restrict__ row_idx,
                               const int* __restrict__ col_idx,
                               float* __restrict__ agg) {
    long long tid = (long long)blockIdx.x * blockDim.x + threadIdx.x;
    long long edge = tid >> 5;          // 32 threads per edge
    if (edge >= NNZ) return;
    int fc = (int)(tid & 31) << 2;      // feature chunk start (0,4,...,124)

    int r = row_idx[edge];
    int c = col_idx[edge];
    if (c >= MEDNUM) c -= MEDNUM;       // embeds1 = concat([mEmbed, mEmbed])
    float v = vals[edge];

    const float4 e = *(const float4*)(mEmbed + (long long)c * FEATDIM + fc);
    float* dst = agg + (long long)r * FEATDIM + fc;
    atomicAdd(dst + 0, v * e.x);
    atomicAdd(dst + 1, v * e.y);
    atomicAdd(dst + 2, v * e.z);
    atomicAdd(dst + 3, v * e.w);
}

// ---------------------------------------------------------------------------
// Kernel 3: epilogue. out = inter*2*relu(agg[:MEDNUM]) + (1-inter)*2*relu(agg[MEDNUM:])
// (relu(leaky_relu(x)) == relu(x); tem1+tem1 == 2*tem1)
// ---------------------------------------------------------------------------
__global__ void epilogue_kernel(const float* __restrict__ agg,
                                const float* __restrict__ inter,
                                float* __restrict__ out) {
    int i = blockIdx.x * blockDim.x + threadIdx.x;
    const int n4 = MEDNUM * FEATDIM / 4;
    if (i >= n4) return;
    float t = inter[0];
    float s1 = 2.f * t;
    float s2 = 2.f * (1.f - t);

    float4 a = ((const float4*)agg)[i];
    float4 b = ((const float4*)(agg + (long long)MEDNUM * FEATDIM))[i];

    float4 o;
    o.x = s1 * fmaxf(a.x, 0.f) + s2 * fmaxf(b.x, 0.f);
    o.y = s1 * fmaxf(a.y, 0.f) + s2 * fmaxf(b.y, 0.f);
    o.z = s1 * fmaxf(a.z, 0.f) + s2 * fmaxf(b.z, 0.f);
    o.w = s1 * fmaxf(a.w, 0.f) + s2 * fmaxf(b.w, 0.f);
    ((float4*)out)[i] = o;
}

extern "C" void kernel_launch(void* const* d_in, const int* in_sizes, int n_in,
                              void* d_out, int out_size, void* d_ws, size_t ws_size,
                              hipStream_t stream) {
    const float* vals   = (const float*)d_in[0];
    const float* mEmbed = (const float*)d_in[1];
    const float* inter  = (const float*)d_in[2];
    const int*   row_idx = (const int*)d_in[3];
    const int*   col_idx = (const int*)d_in[4];
    float* out = (float*)d_out;
    float* agg = (float*)d_ws;   // NROWS*FEATDIM*4 = 51.2 MB scratch

    // 1) zero agg
    {
        int n4 = NROWS * FEATDIM / 4;
        int blocks = (n4 + 255) / 256;
        zero4_kernel<<<blocks, 256, 0, stream>>>((float4*)agg, n4);
    }

    // 2) scatter-add (32 threads/edge)
    {
        long long threads = (long long)NNZ * 32;
        long long blocks = (threads + 255) / 256;
        scatter_kernel<<<(int)blocks, 256, 0, stream>>>(vals, mEmbed, row_idx, col_idx, agg);
    }

    // 3) epilogue
    {
        int n4 = MEDNUM * FEATDIM / 4;
        int blocks = (n4 + 255) / 256;
        epilogue_kernel<<<blocks, 256, 0, stream>>>(agg, inter, out);
    }
}

// Round 2
// 678.359 us; speedup vs baseline: 8.0056x; 8.0056x over previous
//
#include <hip/hip_runtime.h>

#define MEDNUM 50000
#define FEATDIM 128
#define NNZ 3200000
#define NROWS (2 * MEDNUM)
#define SCAN_CHUNK 1024                      // items per scan block (256 thr x 4)
#define NB ((NROWS + SCAN_CHUNK - 1) / SCAN_CHUNK)   // 98 scan blocks

// ws layout (in 4-byte words):
//   row_ptr : [0, 100352)         (NROWS+1 used)
//   cursor  : [100352, 200704)    (NROWS used)
//   blk_sums: [200704, 200832)    (NB used)
//   sorted  : [200832, ...)       (NNZ int2 = 25.6 MB, 8B-aligned: 200832*4 % 8 == 0)
#define OFF_ROWPTR 0
#define OFF_CURSOR 100352
#define OFF_BLKSUM 200704
#define OFF_SORTED 200832

// ---------------------------------------------------------------------------
// 1) zero the histogram counts (stored in row_ptr slots)
// ---------------------------------------------------------------------------
__global__ void zero_counts_kernel(int* __restrict__ counts) {
    int i = blockIdx.x * blockDim.x + threadIdx.x;
    if (i < NROWS) counts[i] = 0;
}

// ---------------------------------------------------------------------------
// 2) histogram of row_idx (int atomics, ~32 hits/bin avg)
// ---------------------------------------------------------------------------
__global__ void hist_kernel(const int* __restrict__ row_idx, int* __restrict__ counts) {
    int e = blockIdx.x * blockDim.x + threadIdx.x;
    if (e < NNZ) atomicAdd(&counts[row_idx[e]], 1);
}

// ---------------------------------------------------------------------------
// 3a) per-block exclusive scan (in place counts->row_ptr), emit block sums
// ---------------------------------------------------------------------------
__global__ void scan1_kernel(int* __restrict__ row_ptr, int* __restrict__ blk_sums) {
    __shared__ int lds[256];
    int b = blockIdx.x, t = threadIdx.x;
    int base = b * SCAN_CHUNK + t * 4;
    int v0 = 0, v1 = 0, v2 = 0, v3 = 0;
    if (base + 0 < NROWS) v0 = row_ptr[base + 0];
    if (base + 1 < NROWS) v1 = row_ptr[base + 1];
    if (base + 2 < NROWS) v2 = row_ptr[base + 2];
    if (base + 3 < NROWS) v3 = row_ptr[base + 3];
    int s = v0 + v1 + v2 + v3;
    lds[t] = s;
    __syncthreads();
    for (int off = 1; off < 256; off <<= 1) {
        int x = 0;
        if (t >= off) x = lds[t - off];
        __syncthreads();
        if (t >= off) lds[t] += x;
        __syncthreads();
    }
    if (t == 255) blk_sums[b] = lds[255];
    int run = lds[t] - s;   // exclusive within block
    if (base + 0 < NROWS) row_ptr[base + 0] = run;  run += v0;
    if (base + 1 < NROWS) row_ptr[base + 1] = run;  run += v1;
    if (base + 2 < NROWS) row_ptr[base + 2] = run;  run += v2;
    if (base + 3 < NROWS) row_ptr[base + 3] = run;
}

// ---------------------------------------------------------------------------
// 3b) scan the block sums (single block; NB=98 <= 128)
// ---------------------------------------------------------------------------
__global__ void scan2_kernel(int* __restrict__ blk_sums) {
    __shared__ int lds[128];
    int t = threadIdx.x;
    int v = (t < NB) ? blk_sums[t] : 0;
    lds[t] = v;
    __syncthreads();
    for (int off = 1; off < 128; off <<= 1) {
        int x = 0;
        if (t >= off) x = lds[t - off];
        __syncthreads();
        if (t >= off) lds[t] += x;
        __syncthreads();
    }
    if (t < NB) blk_sums[t] = lds[t] - v;   // exclusive
}

// ---------------------------------------------------------------------------
// 3c) add block offsets; init cursors; finalize row_ptr[NROWS]
// ---------------------------------------------------------------------------
__global__ void scan3_kernel(int* __restrict__ row_ptr, int* __restrict__ cursor,
                             const int* __restrict__ blk_sums) {
    int i = blockIdx.x * blockDim.x + threadIdx.x;
    if (i < NROWS) {
        int p = row_ptr[i] + blk_sums[i / SCAN_CHUNK];
        row_ptr[i] = p;
        cursor[i] = p;
    }
    if (i == 0) row_ptr[NROWS] = NNZ;   // total is constant
}

// ---------------------------------------------------------------------------
// 4) scatter edges into CSR order: sorted[pos] = {folded_col, val_bits}
// ---------------------------------------------------------------------------
__global__ void scatter_kernel(const float* __restrict__ vals,
                               const int* __restrict__ row_idx,
                               const int* __restrict__ col_idx,
                               int* __restrict__ cursor,
                               int2* __restrict__ sorted) {
    int e = blockIdx.x * blockDim.x + threadIdx.x;
    if (e >= NNZ) return;
    int r = row_idx[e];
    int c = col_idx[e];
    if (c >= MEDNUM) c -= MEDNUM;   // embeds1 = concat([mEmbed, mEmbed])
    int pos = atomicAdd(&cursor[r], 1);
    sorted[pos] = make_int2(c, __float_as_int(vals[e]));
}

// ---------------------------------------------------------------------------
// 5) aggregate: one wave per output row m; accumulates rows m and m+MEDNUM
//    in registers (float2 per lane each), fused relu/scale/mix epilogue.
// ---------------------------------------------------------------------------
__global__ __launch_bounds__(256) void agg_kernel(const int* __restrict__ row_ptr,
                                                  const int2* __restrict__ sorted,
                                                  const float* __restrict__ mEmbed,
                                                  const float* __restrict__ inter,
                                                  float* __restrict__ out) {
    int wave = (blockIdx.x * blockDim.x + threadIdx.x) >> 6;
    int lane = threadIdx.x & 63;
    if (wave >= MEDNUM) return;
    int m = wave;

    float2 acc1 = make_float2(0.f, 0.f);
    float2 acc2 = make_float2(0.f, 0.f);

    // ---- row m ----
    {
        int s = row_ptr[m], eend = row_ptr[m + 1];
        int e = s;
        for (; e + 1 < eend; e += 2) {
            int2 cv0 = sorted[e];
            int2 cv1 = sorted[e + 1];
            const float2 em0 = *(const float2*)(mEmbed + (long long)cv0.x * FEATDIM + lane * 2);
            const float2 em1 = *(const float2*)(mEmbed + (long long)cv1.x * FEATDIM + lane * 2);
            float v0 = __int_as_float(cv0.y);
            float v1 = __int_as_float(cv1.y);
            acc1.x += v0 * em0.x;  acc1.y += v0 * em0.y;
            acc1.x += v1 * em1.x;  acc1.y += v1 * em1.y;
        }
        if (e < eend) {
            int2 cv = sorted[e];
            const float2 em = *(const float2*)(mEmbed + (long long)cv.x * FEATDIM + lane * 2);
            float v = __int_as_float(cv.y);
            acc1.x += v * em.x;  acc1.y += v * em.y;
        }
    }
    // ---- row m + MEDNUM ----
    {
        int s = row_ptr[m + MEDNUM], eend = row_ptr[m + MEDNUM + 1];
        int e = s;
        for (; e + 1 < eend; e += 2) {
            int2 cv0 = sorted[e];
            int2 cv1 = sorted[e + 1];
            const float2 em0 = *(const float2*)(mEmbed + (long long)cv0.x * FEATDIM + lane * 2);
            const float2 em1 = *(const float2*)(mEmbed + (long long)cv1.x * FEATDIM + lane * 2);
            float v0 = __int_as_float(cv0.y);
            float v1 = __int_as_float(cv1.y);
            acc2.x += v0 * em0.x;  acc2.y += v0 * em0.y;
            acc2.x += v1 * em1.x;  acc2.y += v1 * em1.y;
        }
        if (e < eend) {
            int2 cv = sorted[e];
            const float2 em = *(const float2*)(mEmbed + (long long)cv.x * FEATDIM + lane * 2);
            float v = __int_as_float(cv.y);
            acc2.x += v * em.x;  acc2.y += v * em.y;
        }
    }

    float t = inter[0];
    float s1 = 2.f * t;
    float s2 = 2.f * (1.f - t);
    float2 o;
    o.x = s1 * fmaxf(acc1.x, 0.f) + s2 * fmaxf(acc2.x, 0.f);
    o.y = s1 * fmaxf(acc1.y, 0.f) + s2 * fmaxf(acc2.y, 0.f);
    *(float2*)(out + (long long)m * FEATDIM + lane * 2) = o;
}

extern "C" void kernel_launch(void* const* d_in, const int* in_sizes, int n_in,
                              void* d_out, int out_size, void* d_ws, size_t ws_size,
                              hipStream_t stream) {
    const float* vals    = (const float*)d_in[0];
    const float* mEmbed  = (const float*)d_in[1];
    const float* inter   = (const float*)d_in[2];
    const int*   row_idx = (const int*)d_in[3];
    const int*   col_idx = (const int*)d_in[4];
    float* out = (float*)d_out;

    int*  ws       = (int*)d_ws;
    int*  row_ptr  = ws + OFF_ROWPTR;
    int*  cursor   = ws + OFF_CURSOR;
    int*  blk_sums = ws + OFF_BLKSUM;
    int2* sorted   = (int2*)(ws + OFF_SORTED);

    zero_counts_kernel<<<(NROWS + 255) / 256, 256, 0, stream>>>(row_ptr);
    hist_kernel<<<(NNZ + 255) / 256, 256, 0, stream>>>(row_idx, row_ptr);
    scan1_kernel<<<NB, 256, 0, stream>>>(row_ptr, blk_sums);
    scan2_kernel<<<1, 128, 0, stream>>>(blk_sums);
    scan3_kernel<<<(NROWS + 255) / 256, 256, 0, stream>>>(row_ptr, cursor, blk_sums);
    scatter_kernel<<<(NNZ + 255) / 256, 256, 0, stream>>>(vals, row_idx, col_idx, cursor, sorted);
    agg_kernel<<<(MEDNUM * 64 + 255) / 256, 256, 0, stream>>>(row_ptr, sorted, mEmbed, inter, out);
}

// Round 3
// 498.337 us; speedup vs baseline: 10.8975x; 1.3612x over previous
//
#include <hip/hip_runtime.h>

#define MEDNUM 50000
#define FEATDIM 128
#define NNZ 3200000
#define NROWS (2 * MEDNUM)
#define NSLICE 8
#define SLICE_ROWS (NROWS / NSLICE)          // 12500 rows per XCD slice
#define SCAN_CHUNK 1024
#define NB ((NROWS + SCAN_CHUNK - 1) / SCAN_CHUNK)   // 98

// ws layout (4-byte words):
//   row_ptr : [0, 100352)
//   cursor  : [100352, 200704)
//   blk_sums: [200704, 200832)
//   bt      : [200832, 3400832)    bf16 table, 50000*128*2B = 12.8 MB
//   sorted  : [3400832, 9800832)   NNZ int2 = 25.6 MB (byte off 13603328, 8B-aligned)
#define OFF_ROWPTR 0
#define OFF_CURSOR 100352
#define OFF_BLKSUM 200704
#define OFF_BT     200832
#define OFF_SORTED 3400832

// ---------------------------------------------------------------------------
// 0) fp32 -> packed bf16 (RNE) conversion of the embedding table
// ---------------------------------------------------------------------------
__global__ void tobf16_kernel(const float2* __restrict__ in, unsigned int* __restrict__ out) {
    int i = blockIdx.x * blockDim.x + threadIdx.x;
    const int n = MEDNUM * FEATDIM / 2;
    if (i >= n) return;
    float2 f = in[i];
    unsigned int a = __float_as_uint(f.x);
    unsigned int b = __float_as_uint(f.y);
    a = (a + 0x7fffu + ((a >> 16) & 1u)) >> 16;
    b = (b + 0x7fffu + ((b >> 16) & 1u)) >> 16;
    out[i] = a | (b << 16);
}

// ---------------------------------------------------------------------------
// 1) zero histogram counts
// ---------------------------------------------------------------------------
__global__ void zero_counts_kernel(int* __restrict__ counts) {
    int i = blockIdx.x * blockDim.x + threadIdx.x;
    if (i < NROWS) counts[i] = 0;
}

// ---------------------------------------------------------------------------
// 2) histogram of row_idx
// ---------------------------------------------------------------------------
__global__ void hist_kernel(const int* __restrict__ row_idx, int* __restrict__ counts) {
    int e = blockIdx.x * blockDim.x + threadIdx.x;
    if (e < NNZ) atomicAdd(&counts[row_idx[e]], 1);
}

// ---------------------------------------------------------------------------
// 3a) per-block exclusive scan, emit block sums
// ---------------------------------------------------------------------------
__global__ void scan1_kernel(int* __restrict__ row_ptr, int* __restrict__ blk_sums) {
    __shared__ int lds[256];
    int b = blockIdx.x, t = threadIdx.x;
    int base = b * SCAN_CHUNK + t * 4;
    int v0 = 0, v1 = 0, v2 = 0, v3 = 0;
    if (base + 0 < NROWS) v0 = row_ptr[base + 0];
    if (base + 1 < NROWS) v1 = row_ptr[base + 1];
    if (base + 2 < NROWS) v2 = row_ptr[base + 2];
    if (base + 3 < NROWS) v3 = row_ptr[base + 3];
    int s = v0 + v1 + v2 + v3;
    lds[t] = s;
    __syncthreads();
    for (int off = 1; off < 256; off <<= 1) {
        int x = 0;
        if (t >= off) x = lds[t - off];
        __syncthreads();
        if (t >= off) lds[t] += x;
        __syncthreads();
    }
    if (t == 255) blk_sums[b] = lds[255];
    int run = lds[t] - s;
    if (base + 0 < NROWS) row_ptr[base + 0] = run;  run += v0;
    if (base + 1 < NROWS) row_ptr[base + 1] = run;  run += v1;
    if (base + 2 < NROWS) row_ptr[base + 2] = run;  run += v2;
    if (base + 3 < NROWS) row_ptr[base + 3] = run;
}

// ---------------------------------------------------------------------------
// 3b) scan block sums (single block, NB=98 <= 128)
// ---------------------------------------------------------------------------
__global__ void scan2_kernel(int* __restrict__ blk_sums) {
    __shared__ int lds[128];
    int t = threadIdx.x;
    int v = (t < NB) ? blk_sums[t] : 0;
    lds[t] = v;
    __syncthreads();
    for (int off = 1; off < 128; off <<= 1) {
        int x = 0;
        if (t >= off) x = lds[t - off];
        __syncthreads();
        if (t >= off) lds[t] += x;
        __syncthreads();
    }
    if (t < NB) blk_sums[t] = lds[t] - v;
}

// ---------------------------------------------------------------------------
// 3c) add block offsets; init cursors
// ---------------------------------------------------------------------------
__global__ void scan3_kernel(int* __restrict__ row_ptr, int* __restrict__ cursor,
                             const int* __restrict__ blk_sums) {
    int i = blockIdx.x * blockDim.x + threadIdx.x;
    if (i < NROWS) {
        int p = row_ptr[i] + blk_sums[i / SCAN_CHUNK];
        row_ptr[i] = p;
        cursor[i] = p;
    }
    if (i == 0) row_ptr[NROWS] = NNZ;
}

// ---------------------------------------------------------------------------
// 4) XCD-sliced scatter: slice s = blockIdx % 8 handles rows [s*12500,(s+1)*12500).
//    Every slice scans all edges (reads are L3-resident); each slice's writes
//    land in a contiguous ~3.2 MB region that fits the XCD-private L2.
// ---------------------------------------------------------------------------
#define SCAT_EPT 4
__global__ __launch_bounds__(256) void scatter_kernel(const float* __restrict__ vals,
                                                      const int* __restrict__ row_idx,
                                                      const int* __restrict__ col_idx,
                                                      int* __restrict__ cursor,
                                                      int2* __restrict__ sorted) {
    int slice = blockIdx.x & (NSLICE - 1);
    int tile  = blockIdx.x >> 3;
    int base  = tile * (256 * SCAT_EPT);
    int rlo = slice * SLICE_ROWS;
    int rhi = rlo + SLICE_ROWS;
#pragma unroll
    for (int k = 0; k < SCAT_EPT; k++) {
        int e = base + k * 256 + (int)threadIdx.x;
        if (e < NNZ) {
            int r = row_idx[e];
            if (r >= rlo && r < rhi) {
                int c = col_idx[e];
                if (c >= MEDNUM) c -= MEDNUM;
                float v = vals[e];
                int pos = atomicAdd(&cursor[r], 1);
                sorted[pos] = make_int2(c, __float_as_int(v));
            }
        }
    }
}

// ---------------------------------------------------------------------------
// 5) aggregate: one wave per output row m; bf16 embed gathers (256B/edge),
//    4-deep edge unroll for load ILP; fused relu/scale/mix epilogue.
// ---------------------------------------------------------------------------
__device__ __forceinline__ void row_accum(const int* __restrict__ rp,
                                          const int2* __restrict__ sorted,
                                          const unsigned int* __restrict__ bt,
                                          int row, int lane, float& ax, float& ay) {
    int s = rp[row], e = rp[row + 1];
    int i = s;
    for (; i + 4 <= e; i += 4) {
        int2 c0 = sorted[i + 0];
        int2 c1 = sorted[i + 1];
        int2 c2 = sorted[i + 2];
        int2 c3 = sorted[i + 3];
        unsigned int w0 = bt[(long long)c0.x * 64 + lane];
        unsigned int w1 = bt[(long long)c1.x * 64 + lane];
        unsigned int w2 = bt[(long long)c2.x * 64 + lane];
        unsigned int w3 = bt[(long long)c3.x * 64 + lane];
        float v0 = __int_as_float(c0.y), v1 = __int_as_float(c1.y);
        float v2 = __int_as_float(c2.y), v3 = __int_as_float(c3.y);
        ax += v0 * __uint_as_float(w0 << 16);
        ay += v0 * __uint_as_float(w0 & 0xffff0000u);
        ax += v1 * __uint_as_float(w1 << 16);
        ay += v1 * __uint_as_float(w1 & 0xffff0000u);
        ax += v2 * __uint_as_float(w2 << 16);
        ay += v2 * __uint_as_float(w2 & 0xffff0000u);
        ax += v3 * __uint_as_float(w3 << 16);
        ay += v3 * __uint_as_float(w3 & 0xffff0000u);
    }
    for (; i < e; i++) {
        int2 cv = sorted[i];
        unsigned int w = bt[(long long)cv.x * 64 + lane];
        float v = __int_as_float(cv.y);
        ax += v * __uint_as_float(w << 16);
        ay += v * __uint_as_float(w & 0xffff0000u);
    }
}

__global__ __launch_bounds__(256) void agg_kernel(const int* __restrict__ row_ptr,
                                                  const int2* __restrict__ sorted,
                                                  const unsigned int* __restrict__ bt,
                                                  const float* __restrict__ inter,
                                                  float* __restrict__ out) {
    int wave = (blockIdx.x * blockDim.x + threadIdx.x) >> 6;
    int lane = threadIdx.x & 63;
    if (wave >= MEDNUM) return;
    int m = wave;

    float a1x = 0.f, a1y = 0.f, a2x = 0.f, a2y = 0.f;
    row_accum(row_ptr, sorted, bt, m,          lane, a1x, a1y);
    row_accum(row_ptr, sorted, bt, m + MEDNUM, lane, a2x, a2y);

    float t = inter[0];
    float s1 = 2.f * t;
    float s2 = 2.f * (1.f - t);
    float2 o;
    o.x = s1 * fmaxf(a1x, 0.f) + s2 * fmaxf(a2x, 0.f);
    o.y = s1 * fmaxf(a1y, 0.f) + s2 * fmaxf(a2y, 0.f);
    *(float2*)(out + (long long)m * FEATDIM + lane * 2) = o;
}

extern "C" void kernel_launch(void* const* d_in, const int* in_sizes, int n_in,
                              void* d_out, int out_size, void* d_ws, size_t ws_size,
                              hipStream_t stream) {
    const float* vals    = (const float*)d_in[0];
    const float* mEmbed  = (const float*)d_in[1];
    const float* inter   = (const float*)d_in[2];
    const int*   row_idx = (const int*)d_in[3];
    const int*   col_idx = (const int*)d_in[4];
    float* out = (float*)d_out;

    int*  ws       = (int*)d_ws;
    int*  row_ptr  = ws + OFF_ROWPTR;
    int*  cursor   = ws + OFF_CURSOR;
    int*  blk_sums = ws + OFF_BLKSUM;
    unsigned int* bt = (unsigned int*)(ws + OFF_BT);
    int2* sorted   = (int2*)(ws + OFF_SORTED);

    tobf16_kernel<<<(MEDNUM * FEATDIM / 2 + 255) / 256, 256, 0, stream>>>(
        (const float2*)mEmbed, bt);
    zero_counts_kernel<<<(NROWS + 255) / 256, 256, 0, stream>>>(row_ptr);
    hist_kernel<<<(NNZ + 255) / 256, 256, 0, stream>>>(row_idx, row_ptr);
    scan1_kernel<<<NB, 256, 0, stream>>>(row_ptr, blk_sums);
    scan2_kernel<<<1, 128, 0, stream>>>(blk_sums);
    scan3_kernel<<<(NROWS + 255) / 256, 256, 0, stream>>>(row_ptr, cursor, blk_sums);
    {
        int tiles = (NNZ + 256 * SCAT_EPT - 1) / (256 * SCAT_EPT);   // 3125
        scatter_kernel<<<tiles * NSLICE, 256, 0, stream>>>(vals, row_idx, col_idx, cursor, sorted);
    }
    agg_kernel<<<(MEDNUM * 64 + 255) / 256, 256, 0, stream>>>(row_ptr, sorted, bt, inter, out);
}